// Round 1
// baseline (1528.893 us; speedup 1.0000x reference)
//
#include <hip/hip_runtime.h>
#include <hip/hip_bf16.h>

// Problem constants
#define DIM   4096
#define SEQ   2048
#define NH    32
#define HD    128
#define BSZ   2
#define SEG   16777216   // 4096*4096 elements (x, each weight, each activation)

typedef unsigned short u16;
typedef unsigned int   u32;
typedef __attribute__((ext_vector_type(8))) short bf16x8;
typedef __attribute__((ext_vector_type(4))) float f32x4;
typedef __attribute__((ext_vector_type(4))) u16   u16x4;

__device__ __forceinline__ float b2f(u16 u) {
    union { u32 i; float f; } c; c.i = ((u32)u) << 16; return c.f;
}
__device__ __forceinline__ u16 f2b(float f) {
    u32 x = __float_as_uint(f);
    return (u16)((x + 0x7FFFu + ((x >> 16) & 1u)) >> 16);  // RNE
}
__device__ __forceinline__ void gload_lds16(const void* g, void* l) {
    __builtin_amdgcn_global_load_lds(
        (__attribute__((address_space(1))) void*)(unsigned long)(g),
        (__attribute__((address_space(3))) void*)(l), 16, 0, 0);
}

// ---------------------------------------------------------------------------
// 1) cast x + wq + wk + wv + wo (fp32) -> bf16, contiguous into ws segments 0..4
// ---------------------------------------------------------------------------
__global__ __launch_bounds__(256) void cast5(const float* __restrict__ x,
                                             const float* __restrict__ wq,
                                             const float* __restrict__ wk,
                                             const float* __restrict__ wv,
                                             const float* __restrict__ wo,
                                             u16* __restrict__ dst) {
    int i = blockIdx.x * 1024 + threadIdx.x * 4;   // 4 elems per thread
    int seg = i >> 24;                              // SEG == 2^24
    int off = i & (SEG - 1);
    const float* s = x;
    if (seg == 1) s = wq; else if (seg == 2) s = wk;
    else if (seg == 3) s = wv; else if (seg == 4) s = wo;
    float4 v = *(const float4*)(s + off);
    u16x4 o; o.x = f2b(v.x); o.y = f2b(v.y); o.z = f2b(v.z); o.w = f2b(v.w);
    *(u16x4*)(dst + i) = o;
}

// ---------------------------------------------------------------------------
// 2) GEMM  C[M,N] = A[M,K] * B[N,K]^T   (bf16 in, bf16 or fp32 out)
//    m97 structure: 128x128 tile, BK=32, global_load_lds width 16,
//    XOR chunk swizzle to break ds_read_b128 bank conflicts.
//    grid: (N/128, M/128, nz); B/C advanced by z*SEG.
// ---------------------------------------------------------------------------
template<int OUT_BF16>
__global__ __launch_bounds__(256) void gemm_bt(const u16* __restrict__ A,
                                               const u16* __restrict__ Bbase,
                                               void* __restrict__ Cv) {
    __shared__ __align__(16) u16 smem[8192];   // A-tile [128][32] then B-tile [128][32]
    const int tid = threadIdx.x;
    const int lane = tid & 63, w = tid >> 6;
    const int quad = lane >> 4, m16 = lane & 15;
    const int m0 = blockIdx.y * 128, n0 = blockIdx.x * 128;
    const int wm = (w & 1) * 64, wn = (w >> 1) * 64;
    const u16* B = Bbase + (size_t)blockIdx.z * SEG;

    f32x4 acc[4][4];
    for (int a = 0; a < 4; ++a) for (int b = 0; b < 4; ++b) acc[a][b] = 0.f;

    const int gbase = w * 256 + lane;   // granule id base for this lane

    for (int k0 = 0; k0 < DIM; k0 += 32) {
        __syncthreads();
        // stage 16 KB: granule g (16B): g<512 -> A row g>>2, else B row (g>>2)&127
        for (int j = 0; j < 4; ++j) {
            int g = gbase + j * 64;
            int row = (g >> 2) & 127;
            int ch = (g & 3) ^ ((row >> 1) & 3);      // XOR swizzle
            const u16* src = (g < 512 ? A + (m0 + row) * DIM : B + (n0 + row) * DIM)
                             + k0 + ch * 8;
            gload_lds16(src, (char*)smem + w * 4096 + j * 1024);
        }
        __syncthreads();

        bf16x8 af[4], bfr[4];
        for (int mt = 0; mt < 4; ++mt) {
            int row = wm + mt * 16 + m16;
            int ch = quad ^ ((row >> 1) & 3);
            af[mt] = *(const bf16x8*)(smem + row * 32 + ch * 8);
        }
        for (int nt = 0; nt < 4; ++nt) {
            int row = wn + nt * 16 + m16;
            int ch = quad ^ ((row >> 1) & 3);
            bfr[nt] = *(const bf16x8*)(smem + 4096 + row * 32 + ch * 8);
        }
        for (int mt = 0; mt < 4; ++mt)
            for (int nt = 0; nt < 4; ++nt)
                acc[mt][nt] = __builtin_amdgcn_mfma_f32_16x16x32_bf16(
                    af[mt], bfr[nt], acc[mt][nt], 0, 0, 0);
    }

    // epilogue: D row=(quad*4+r) [m], col=m16 [n]
    for (int mt = 0; mt < 4; ++mt) for (int nt = 0; nt < 4; ++nt) {
        int row = m0 + wm + mt * 16 + quad * 4;
        int col = n0 + wn + nt * 16 + m16;
        if (OUT_BF16) {
            u16* C = (u16*)Cv + (size_t)blockIdx.z * SEG;
            for (int r = 0; r < 4; ++r) C[(row + r) * DIM + col] = f2b(acc[mt][nt][r]);
        } else {
            float* C = (float*)Cv + (size_t)blockIdx.z * SEG;
            for (int r = 0; r < 4; ++r) C[(row + r) * DIM + col] = acc[mt][nt][r];
        }
    }
}

// ---------------------------------------------------------------------------
// 3) RoPE on xq, xk. Writes q_b, k_b (bf16) and new_hidden[0] (fp32).
//    One thread per (b,s,h,pair).
// ---------------------------------------------------------------------------
__global__ __launch_bounds__(256) void rope(const u16* __restrict__ XQ,
                                            const u16* __restrict__ XK,
                                            const float* __restrict__ FC,
                                            u16* __restrict__ Qo,
                                            u16* __restrict__ Ko,
                                            float* __restrict__ KH) {
    int tid = blockIdx.x * 256 + threadIdx.x;   // ((b*S+s)*NH+h)*64 + i
    int i = tid & 63;
    int s = (tid >> 11) & 2047;
    float2 cs = *(const float2*)(FC + (s * 64 + i) * 2);
    u32 q = ((const u32*)XQ)[tid];
    u32 k = ((const u32*)XK)[tid];
    float q0 = b2f((u16)(q & 0xffff)), q1 = b2f((u16)(q >> 16));
    float k0 = b2f((u16)(k & 0xffff)), k1 = b2f((u16)(k >> 16));
    float qr = q0 * cs.x - q1 * cs.y, qi = q0 * cs.y + q1 * cs.x;
    float kr = k0 * cs.x - k1 * cs.y, ki = k0 * cs.y + k1 * cs.x;
    ((u32*)Qo)[tid] = (u32)f2b(qr) | ((u32)f2b(qi) << 16);
    ((u32*)Ko)[tid] = (u32)f2b(kr) | ((u32)f2b(ki) << 16);
    *(float2*)(KH + (size_t)tid * 2) = make_float2(kr, ki);
}

// ---------------------------------------------------------------------------
// 4) V prep: new_hidden[1] (fp32, [b][s][h][d]) + transposed Vt (bf16, [bh][d][s])
// ---------------------------------------------------------------------------
__global__ __launch_bounds__(256) void vprep(const u16* __restrict__ XV,
                                             float* __restrict__ VH,
                                             u16* __restrict__ VT) {
    __shared__ u16 tile[64][65];
    int bs = blockIdx.x;        // s-tile (32)
    int bd = blockIdx.y;        // d-tile (2)
    int bh = blockIdx.z;        // (64)
    int b = bh >> 5, h = bh & 31;
    int t = threadIdx.x;
    int c = t & 63, r4 = t >> 6;
    for (int i = 0; i < 16; ++i) {
        int sr = i * 4 + r4;
        int gi = ((b * SEQ + bs * 64 + sr) * NH + h) * HD + bd * 64 + c;
        u16 v = XV[gi];
        VH[gi] = b2f(v);
        tile[sr][c] = v;
    }
    __syncthreads();
    for (int i = 0; i < 16; ++i) {
        int dr = i * 4 + r4;
        VT[(bh * HD + bd * 64 + dr) * SEQ + bs * 64 + c] = tile[c][dr];
    }
}

// ---------------------------------------------------------------------------
// 5) Causal flash attention. Block = 64 q-rows (4 waves x 16), KV tile = 64.
//    Q,K in [b][s][h][d] bf16; Vt in [bh][d][s] bf16; O in [b][s][h][d] bf16.
// ---------------------------------------------------------------------------
__global__ __launch_bounds__(256) void flash(const u16* __restrict__ Q,
                                             const u16* __restrict__ K,
                                             const u16* __restrict__ Vt,
                                             u16* __restrict__ O) {
    __shared__ __align__(16) u16 k_lds[64 * 136];    // 64 rows(s) x 128(d), stride 136
    __shared__ __align__(16) u16 v_lds[128 * 72];    // 128 rows(d) x 64(s), stride 72
    __shared__ __align__(16) u16 p_lds[4][16 * 72];  // per-wave P 16x64, stride 72

    const int tid = threadIdx.x, lane = tid & 63, w = tid >> 6;
    const int quad = lane >> 4, m16 = lane & 15;
    const int qt = blockIdx.x;          // q-tile 0..31
    const int bh = blockIdx.y;          // 0..63
    const int b = bh >> 5, h = bh & 31;
    const int q0 = qt * 64;
    const int qrow = q0 + w * 16;

    // Q fragments, kept in registers for all K tiles
    bf16x8 qa[4];
    {
        const u16* qp = Q + ((b * SEQ + qrow + m16) * NH + h) * HD;
        for (int ks = 0; ks < 4; ++ks) qa[ks] = *(const bf16x8*)(qp + ks * 32 + quad * 8);
    }
    float mi[4], li[4];
    f32x4 o[8];
    for (int r = 0; r < 4; ++r) { mi[r] = -1e30f; li[r] = 0.f; }
    for (int n = 0; n < 8; ++n) o[n] = 0.f;

    const float scale = 0.08838834764831845f;   // 1/sqrt(128)

    for (int kt = 0; kt <= qt; ++kt) {
        const int k0 = kt * 64;
        __syncthreads();
        {   // stage K tile: 64 rows x 128 d
            int row = tid >> 2, seg = tid & 3;
            const u16* src = K + ((b * SEQ + k0 + row) * NH + h) * HD + seg * 32;
            u16* dst = k_lds + row * 136 + seg * 32;
            bf16x8 t0 = *(const bf16x8*)(src);
            bf16x8 t1 = *(const bf16x8*)(src + 8);
            bf16x8 t2 = *(const bf16x8*)(src + 16);
            bf16x8 t3 = *(const bf16x8*)(src + 24);
            *(bf16x8*)(dst) = t0; *(bf16x8*)(dst + 8) = t1;
            *(bf16x8*)(dst + 16) = t2; *(bf16x8*)(dst + 24) = t3;
        }
        {   // stage Vt tile: 128 rows(d) x 64 s
            int row = tid >> 1, seg = tid & 1;
            const u16* src = Vt + (bh * HD + row) * SEQ + k0 + seg * 32;
            u16* dst = v_lds + row * 72 + seg * 32;
            bf16x8 t0 = *(const bf16x8*)(src);
            bf16x8 t1 = *(const bf16x8*)(src + 8);
            bf16x8 t2 = *(const bf16x8*)(src + 16);
            bf16x8 t3 = *(const bf16x8*)(src + 24);
            *(bf16x8*)(dst) = t0; *(bf16x8*)(dst + 8) = t1;
            *(bf16x8*)(dst + 16) = t2; *(bf16x8*)(dst + 24) = t3;
        }
        __syncthreads();

        // QK^T : S (16 q-rows x 64 k-cols) per wave
        f32x4 s[4];
        for (int nt = 0; nt < 4; ++nt) {
            s[nt] = 0.f;
            for (int ks = 0; ks < 4; ++ks) {
                bf16x8 kb = *(const bf16x8*)(k_lds + (nt * 16 + m16) * 136 + ks * 32 + quad * 8);
                s[nt] = __builtin_amdgcn_mfma_f32_16x16x32_bf16(qa[ks], kb, s[nt], 0, 0, 0);
            }
        }

        float sv[4][4];
        for (int nt = 0; nt < 4; ++nt)
            for (int r = 0; r < 4; ++r) {
                float v = s[nt][r] * scale;
                if (kt == qt) {
                    int col = k0 + nt * 16 + m16;
                    int rq = qrow + quad * 4 + r;
                    if (col > rq) v = -1e30f;
                }
                sv[nt][r] = v;
            }

        for (int r = 0; r < 4; ++r) {
            float mx = fmaxf(fmaxf(sv[0][r], sv[1][r]), fmaxf(sv[2][r], sv[3][r]));
            for (int off = 8; off >= 1; off >>= 1) mx = fmaxf(mx, __shfl_xor(mx, off));
            float mnew = fmaxf(mi[r], mx);
            float alpha = __expf(mi[r] - mnew);
            float sum = 0.f;
            for (int nt = 0; nt < 4; ++nt) {
                float pv = __expf(sv[nt][r] - mnew);
                sum += pv;
                p_lds[w][(quad * 4 + r) * 72 + nt * 16 + m16] = f2b(pv);
            }
            for (int off = 8; off >= 1; off >>= 1) sum += __shfl_xor(sum, off);
            li[r] = li[r] * alpha + sum;
            mi[r] = mnew;
            for (int n8 = 0; n8 < 8; ++n8) o[n8][r] *= alpha;
        }

        // ensure P writes visible to our own ds_reads (in-order LDS + explicit wait)
        asm volatile("s_waitcnt lgkmcnt(0)" ::: "memory");

        // PV : O += P (16x64) * Vt-tile (64 x 128)
        for (int ks2 = 0; ks2 < 2; ++ks2) {
            bf16x8 pa = *(const bf16x8*)(&p_lds[w][0] + m16 * 72 + ks2 * 32 + quad * 8);
            for (int n8 = 0; n8 < 8; ++n8) {
                bf16x8 vb = *(const bf16x8*)(v_lds + (n8 * 16 + m16) * 72 + ks2 * 32 + quad * 8);
                o[n8] = __builtin_amdgcn_mfma_f32_16x16x32_bf16(pa, vb, o[n8], 0, 0, 0);
            }
        }
    }

    for (int n8 = 0; n8 < 8; ++n8)
        for (int r = 0; r < 4; ++r) {
            int rq = qrow + quad * 4 + r;
            float val = o[n8][r] / li[r];
            O[((b * SEQ + rq) * NH + h) * HD + n8 * 16 + m16] = f2b(val);
        }
}

// ---------------------------------------------------------------------------
// launch
// ws layout (bf16 elems, SEG=16777216 each; 8 segs = 268 MB):
//  0: x_b   (later reused as q_rope)
//  1: wq_b  (later reused as k_rope)
//  2: wk_b  (later reused as Vt)
//  3: wv_b  (later reused as attn_out)
//  4: wo_b
//  5: xq_b   6: xk_b   7: xv_b
// ---------------------------------------------------------------------------
extern "C" void kernel_launch(void* const* d_in, const int* in_sizes, int n_in,
                              void* d_out, int out_size, void* d_ws, size_t ws_size,
                              hipStream_t stream) {
    const float* x  = (const float*)d_in[0];
    const float* fc = (const float*)d_in[1];
    const float* wq = (const float*)d_in[4];
    const float* wk = (const float*)d_in[5];
    const float* wv = (const float*)d_in[6];
    const float* wo = (const float*)d_in[7];

    float* out = (float*)d_out;
    float* kh  = out + 16777216;             // new_hidden[0]
    float* vh  = out + 33554432;             // new_hidden[1]

    u16* ws = (u16*)d_ws;
    u16* xb  = ws + 0L * SEG;
    u16* wqb = ws + 1L * SEG;
    u16* wkb = ws + 2L * SEG;
    u16* wvb = ws + 3L * SEG;
    u16* wob = ws + 4L * SEG;
    u16* xqb = ws + 5L * SEG;
    // xkb = ws + 6L*SEG, xvb = ws + 7L*SEG (contiguous after xqb for z-indexed GEMM)
    u16* xkb = ws + 6L * SEG;
    u16* xvb = ws + 7L * SEG;
    u16* qro = xb;    // q after rope
    u16* kro = wqb;   // k after rope
    u16* vt  = wkb;   // transposed V
    u16* ao  = wvb;   // attention output

    // 1) casts
    cast5<<<dim3(81920), dim3(256), 0, stream>>>(x, wq, wk, wv, wo, ws);

    // 2) QKV GEMMs (z selects weight seg 1..3 via Bbase=wqb, out seg 5..7)
    gemm_bt<1><<<dim3(32, 32, 3), dim3(256), 0, stream>>>(xb, wqb, (void*)xqb);

    // 3) RoPE (+ fp32 K into new_hidden[0])
    rope<<<dim3(32768), dim3(256), 0, stream>>>(xqb, xkb, fc, qro, kro, kh);

    // 4) V: fp32 into new_hidden[1] + bf16 transpose
    vprep<<<dim3(32, 2, 64), dim3(256), 0, stream>>>(xvb, vh, vt);

    // 5) flash attention
    flash<<<dim3(32, 64), dim3(256), 0, stream>>>(qro, kro, vt, ao);

    // 6) output GEMM (fp32 out)
    gemm_bt<0><<<dim3(32, 32, 1), dim3(256), 0, stream>>>(ao, wob, (void*)out);
}

// Round 2
// 1339.659 us; speedup vs baseline: 1.1413x; 1.1413x over previous
//
#include <hip/hip_runtime.h>
#include <hip/hip_bf16.h>

// Problem constants
#define DIM   4096
#define SEQ   2048
#define NH    32
#define HD    128
#define BSZ   2
#define SEG   16777216   // 4096*4096 elements (x, each weight, each activation)

typedef unsigned short u16;
typedef unsigned int   u32;
typedef __attribute__((ext_vector_type(8))) short bf16x8;
typedef __attribute__((ext_vector_type(4))) float f32x4;
typedef __attribute__((ext_vector_type(4))) u16   u16x4;

__device__ __forceinline__ float b2f(u16 u) {
    union { u32 i; float f; } c; c.i = ((u32)u) << 16; return c.f;
}
__device__ __forceinline__ u16 f2b(float f) {
    u32 x = __float_as_uint(f);
    return (u16)((x + 0x7FFFu + ((x >> 16) & 1u)) >> 16);  // RNE
}
__device__ __forceinline__ void gload_lds16(const void* g, void* l) {
    __builtin_amdgcn_global_load_lds(
        (__attribute__((address_space(1))) void*)(unsigned long)(g),
        (__attribute__((address_space(3))) void*)(l), 16, 0, 0);
}

// ---------------------------------------------------------------------------
// 1) cast x + wq + wk + wv + wo (fp32) -> bf16, contiguous into ws segments 0..4
// ---------------------------------------------------------------------------
__global__ __launch_bounds__(256) void cast5(const float* __restrict__ x,
                                             const float* __restrict__ wq,
                                             const float* __restrict__ wk,
                                             const float* __restrict__ wv,
                                             const float* __restrict__ wo,
                                             u16* __restrict__ dst) {
    int i = blockIdx.x * 1024 + threadIdx.x * 4;   // 4 elems per thread
    int seg = i >> 24;                              // SEG == 2^24
    int off = i & (SEG - 1);
    const float* s = x;
    if (seg == 1) s = wq; else if (seg == 2) s = wk;
    else if (seg == 3) s = wv; else if (seg == 4) s = wo;
    float4 v = *(const float4*)(s + off);
    u16x4 o; o.x = f2b(v.x); o.y = f2b(v.y); o.z = f2b(v.z); o.w = f2b(v.w);
    *(u16x4*)(dst + i) = o;
}

// ---------------------------------------------------------------------------
// 2) GEMM  C[M,N] = A[M,K] * B[N,K]^T   (bf16 in, bf16 or fp32 out)
//    m97 structure: 128x128 tile, BK=32, global_load_lds width 16,
//    XOR chunk swizzle. grid: (N/128, M/128, nz); B/C advanced by z*SEG.
// ---------------------------------------------------------------------------
template<int OUT_BF16>
__global__ __launch_bounds__(256) void gemm_bt(const u16* __restrict__ A,
                                               const u16* __restrict__ Bbase,
                                               void* __restrict__ Cv) {
    __shared__ __align__(16) u16 smem[8192];   // A-tile [128][32] then B-tile [128][32]
    const int tid = threadIdx.x;
    const int lane = tid & 63, w = tid >> 6;
    const int quad = lane >> 4, m16 = lane & 15;
    const int m0 = blockIdx.y * 128, n0 = blockIdx.x * 128;
    const int wm = (w & 1) * 64, wn = (w >> 1) * 64;
    const u16* B = Bbase + (size_t)blockIdx.z * SEG;

    f32x4 acc[4][4];
    for (int a = 0; a < 4; ++a) for (int b = 0; b < 4; ++b) acc[a][b] = 0.f;

    const int gbase = w * 256 + lane;   // granule id base for this lane

    for (int k0 = 0; k0 < DIM; k0 += 32) {
        __syncthreads();
        for (int j = 0; j < 4; ++j) {
            int g = gbase + j * 64;
            int row = (g >> 2) & 127;
            int ch = (g & 3) ^ ((row >> 1) & 3);      // XOR swizzle
            const u16* src = (g < 512 ? A + (m0 + row) * DIM : B + (n0 + row) * DIM)
                             + k0 + ch * 8;
            gload_lds16(src, (char*)smem + w * 4096 + j * 1024);
        }
        __syncthreads();

        bf16x8 af[4], bfr[4];
        for (int mt = 0; mt < 4; ++mt) {
            int row = wm + mt * 16 + m16;
            int ch = quad ^ ((row >> 1) & 3);
            af[mt] = *(const bf16x8*)(smem + row * 32 + ch * 8);
        }
        for (int nt = 0; nt < 4; ++nt) {
            int row = wn + nt * 16 + m16;
            int ch = quad ^ ((row >> 1) & 3);
            bfr[nt] = *(const bf16x8*)(smem + 4096 + row * 32 + ch * 8);
        }
        for (int mt = 0; mt < 4; ++mt)
            for (int nt = 0; nt < 4; ++nt)
                acc[mt][nt] = __builtin_amdgcn_mfma_f32_16x16x32_bf16(
                    af[mt], bfr[nt], acc[mt][nt], 0, 0, 0);
    }

    for (int mt = 0; mt < 4; ++mt) for (int nt = 0; nt < 4; ++nt) {
        int row = m0 + wm + mt * 16 + quad * 4;
        int col = n0 + wn + nt * 16 + m16;
        if (OUT_BF16) {
            u16* C = (u16*)Cv + (size_t)blockIdx.z * SEG;
            for (int r = 0; r < 4; ++r) C[(row + r) * DIM + col] = f2b(acc[mt][nt][r]);
        } else {
            float* C = (float*)Cv + (size_t)blockIdx.z * SEG;
            for (int r = 0; r < 4; ++r) C[(row + r) * DIM + col] = acc[mt][nt][r];
        }
    }
}

// ---------------------------------------------------------------------------
// 3) RoPE on xq, xk. Writes q_b, k_b (bf16) and new_hidden[0] (fp32).
// ---------------------------------------------------------------------------
__global__ __launch_bounds__(256) void rope(const u16* __restrict__ XQ,
                                            const u16* __restrict__ XK,
                                            const float* __restrict__ FC,
                                            u16* __restrict__ Qo,
                                            u16* __restrict__ Ko,
                                            float* __restrict__ KH) {
    int tid = blockIdx.x * 256 + threadIdx.x;   // ((b*S+s)*NH+h)*64 + i
    int i = tid & 63;
    int s = (tid >> 11) & 2047;
    float2 cs = *(const float2*)(FC + (s * 64 + i) * 2);
    u32 q = ((const u32*)XQ)[tid];
    u32 k = ((const u32*)XK)[tid];
    float q0 = b2f((u16)(q & 0xffff)), q1 = b2f((u16)(q >> 16));
    float k0 = b2f((u16)(k & 0xffff)), k1 = b2f((u16)(k >> 16));
    float qr = q0 * cs.x - q1 * cs.y, qi = q0 * cs.y + q1 * cs.x;
    float kr = k0 * cs.x - k1 * cs.y, ki = k0 * cs.y + k1 * cs.x;
    ((u32*)Qo)[tid] = (u32)f2b(qr) | ((u32)f2b(qi) << 16);
    ((u32*)Ko)[tid] = (u32)f2b(kr) | ((u32)f2b(ki) << 16);
    *(float2*)(KH + (size_t)tid * 2) = make_float2(kr, ki);
}

// ---------------------------------------------------------------------------
// 4) V prep: new_hidden[1] (fp32) + transposed Vt (bf16, [bh][d][s])
// ---------------------------------------------------------------------------
__global__ __launch_bounds__(256) void vprep(const u16* __restrict__ XV,
                                             float* __restrict__ VH,
                                             u16* __restrict__ VT) {
    __shared__ u16 tile[64][65];
    int bs = blockIdx.x;        // s-tile (32)
    int bd = blockIdx.y;        // d-tile (2)
    int bh = blockIdx.z;        // (64)
    int b = bh >> 5, h = bh & 31;
    int t = threadIdx.x;
    int c = t & 63, r4 = t >> 6;
    for (int i = 0; i < 16; ++i) {
        int sr = i * 4 + r4;
        int gi = ((b * SEQ + bs * 64 + sr) * NH + h) * HD + bd * 64 + c;
        u16 v = XV[gi];
        VH[gi] = b2f(v);
        tile[sr][c] = v;
    }
    __syncthreads();
    for (int i = 0; i < 16; ++i) {
        int dr = i * 4 + r4;
        VT[(bh * HD + bd * 64 + dr) * SEQ + bs * 64 + c] = tile[c][dr];
    }
}

// ---------------------------------------------------------------------------
// 5) Causal flash attention v2.
//    Block = 128 q-rows, 4 waves x 32 rows (2 m-frags). KV tile = 64.
//    K/V staged by global_load_lds (XOR chunk swizzle, unpadded layouts).
//    k_lds[64 s][128 d]  chunk swizzle p = c ^ (s&15)
//    v_lds[128 d][64 s]  chunk swizzle p = c ^ (d&7)
//    p_lds per-wave [32 q][64 s], stride 68 (bank spread)
// ---------------------------------------------------------------------------
__global__ __launch_bounds__(256, 2) void flash(const u16* __restrict__ Q,
                                                const u16* __restrict__ K,
                                                const u16* __restrict__ Vt,
                                                u16* __restrict__ O) {
    __shared__ __align__(16) u16 k_lds[64 * 128];
    __shared__ __align__(16) u16 v_lds[128 * 64];
    __shared__ __align__(16) u16 p_lds[4][32 * 68];

    const int tid = threadIdx.x, lane = tid & 63, w = tid >> 6;
    const int quad = lane >> 4, m16 = lane & 15;
    const int bh = blockIdx.x;                 // 0..63
    const int b = bh >> 5, h = bh & 31;
    const int qt = (gridDim.y - 1) - blockIdx.y;   // long blocks dispatch first
    const int q0 = qt * 128;
    const int wrow = q0 + w * 32;              // this wave's 32 q-rows

    // staging coords (constant per thread)
    const int gk = w * 256 + lane;             // K granule base (j adds 64)
    // Q fragments (2 m-frags x 4 k-chunks), kept in registers
    bf16x8 qa[2][4];
#pragma unroll
    for (int mt = 0; mt < 2; ++mt) {
        const u16* qp = Q + ((size_t)(b * SEQ + wrow + mt * 16 + m16) * NH + h) * HD;
#pragma unroll
        for (int ks = 0; ks < 4; ++ks) qa[mt][ks] = *(const bf16x8*)(qp + ks * 32 + quad * 8);
    }

    float mi[2][4], li[2][4];
    f32x4 o[2][8];
#pragma unroll
    for (int mt = 0; mt < 2; ++mt)
#pragma unroll
        for (int r = 0; r < 4; ++r) { mi[mt][r] = -1e30f; li[mt][r] = 0.f; }
#pragma unroll
    for (int mt = 0; mt < 2; ++mt)
#pragma unroll
        for (int n = 0; n < 8; ++n) o[mt][n] = 0.f;

    const float scale = 0.08838834764831845f;   // 1/sqrt(128)
    const int nkt = 2 * qt + 2;

    const u16* Kbase = K + ((size_t)(b * SEQ) * NH + h) * HD;
    const u16* Vbase = Vt + (size_t)(bh * HD) * SEQ;

    for (int kt = 0; kt < nkt; ++kt) {
        const int k0 = kt * 64;
        __syncthreads();
        // ---- stage K tile (1024 granules) + V tile (1024 granules) via DMA
#pragma unroll
        for (int j = 0; j < 4; ++j) {
            int g = gk + j * 64;
            int r = g >> 4, p = g & 15, c = p ^ (r & 15);
            gload_lds16(Kbase + (size_t)(k0 + r) * DIM + c * 8,
                        (char*)k_lds + w * 4096 + j * 1024);
        }
#pragma unroll
        for (int j = 0; j < 4; ++j) {
            int g = gk + j * 64;
            int r = g >> 3, p = g & 7, c = p ^ (r & 7);
            gload_lds16(Vbase + (size_t)r * SEQ + k0 + c * 8,
                        (char*)v_lds + w * 4096 + j * 1024);
        }
        __syncthreads();

        if (k0 > wrow + 31) continue;   // fully-masked for this wave (uniform)

        // ---- QK^T : S (2 x 16 q-rows) x 64 k-cols
        f32x4 s[2][4];
#pragma unroll
        for (int mt = 0; mt < 2; ++mt)
#pragma unroll
            for (int nt = 0; nt < 4; ++nt) s[mt][nt] = 0.f;
#pragma unroll
        for (int ks = 0; ks < 4; ++ks)
#pragma unroll
            for (int nt = 0; nt < 4; ++nt) {
                int rk = nt * 16 + m16;
                int p = (ks * 4 + quad) ^ m16;
                bf16x8 kb = *(const bf16x8*)(k_lds + rk * 128 + p * 8);
#pragma unroll
                for (int mt = 0; mt < 2; ++mt)
                    s[mt][nt] = __builtin_amdgcn_mfma_f32_16x16x32_bf16(
                        qa[mt][ks], kb, s[mt][nt], 0, 0, 0);
            }

        // ---- online softmax per m-frag
#pragma unroll
        for (int mt = 0; mt < 2; ++mt) {
            float sv[4][4];
            const bool need_mask = (k0 + 63) > (wrow + mt * 16);
#pragma unroll
            for (int nt = 0; nt < 4; ++nt)
#pragma unroll
                for (int r = 0; r < 4; ++r) {
                    float v = s[mt][nt][r] * scale;
                    if (need_mask) {
                        int col = k0 + nt * 16 + m16;
                        int rq = wrow + mt * 16 + quad * 4 + r;
                        if (col > rq) v = -1e30f;
                    }
                    sv[nt][r] = v;
                }
#pragma unroll
            for (int r = 0; r < 4; ++r) {
                float mx = fmaxf(fmaxf(sv[0][r], sv[1][r]), fmaxf(sv[2][r], sv[3][r]));
#pragma unroll
                for (int off = 8; off >= 1; off >>= 1) mx = fmaxf(mx, __shfl_xor(mx, off));
                float mnew = fmaxf(mi[mt][r], mx);
                float alpha = __expf(mi[mt][r] - mnew);
                float sum = 0.f;
#pragma unroll
                for (int nt = 0; nt < 4; ++nt) {
                    float pv = __expf(sv[nt][r] - mnew);
                    sum += pv;
                    p_lds[w][(mt * 16 + quad * 4 + r) * 68 + nt * 16 + m16] = f2b(pv);
                }
#pragma unroll
                for (int off = 8; off >= 1; off >>= 1) sum += __shfl_xor(sum, off);
                li[mt][r] = li[mt][r] * alpha + sum;
                mi[mt][r] = mnew;
#pragma unroll
                for (int n8 = 0; n8 < 8; ++n8) o[mt][n8][r] *= alpha;
            }
        }

        // own-wave LDS ordering: P writes -> P reads
        asm volatile("s_waitcnt lgkmcnt(0)" ::: "memory");

        // ---- PV : O += P (2x16 x 64) * V-tile (64 x 128)
#pragma unroll
        for (int ks2 = 0; ks2 < 2; ++ks2) {
            bf16x8 pa[2];
#pragma unroll
            for (int mt = 0; mt < 2; ++mt)
                pa[mt] = *(const bf16x8*)(&p_lds[w][0] + (mt * 16 + m16) * 68 + ks2 * 32 + quad * 8);
#pragma unroll
            for (int n8 = 0; n8 < 8; ++n8) {
                int rv = n8 * 16 + m16;
                int p = (ks2 * 4 + quad) ^ (m16 & 7);
                bf16x8 vb = *(const bf16x8*)(v_lds + rv * 64 + p * 8);
#pragma unroll
                for (int mt = 0; mt < 2; ++mt)
                    o[mt][n8] = __builtin_amdgcn_mfma_f32_16x16x32_bf16(
                        pa[mt], vb, o[mt][n8], 0, 0, 0);
            }
        }
    }

#pragma unroll
    for (int mt = 0; mt < 2; ++mt) {
        float inv[4];
#pragma unroll
        for (int r = 0; r < 4; ++r) inv[r] = 1.0f / li[mt][r];
#pragma unroll
        for (int n8 = 0; n8 < 8; ++n8)
#pragma unroll
            for (int r = 0; r < 4; ++r) {
                int rq = wrow + mt * 16 + quad * 4 + r;
                O[((size_t)(b * SEQ + rq) * NH + h) * HD + n8 * 16 + m16] =
                    f2b(o[mt][n8][r] * inv[r]);
            }
    }
}

// ---------------------------------------------------------------------------
// launch — ws layout (bf16 elems, SEG each):
//  0: x_b (→ q_rope)  1: wq_b (→ k_rope)  2: wk_b (→ Vt)  3: wv_b (→ attn_out)
//  4: wo_b  5: xq_b  6: xk_b  7: xv_b
// ---------------------------------------------------------------------------
extern "C" void kernel_launch(void* const* d_in, const int* in_sizes, int n_in,
                              void* d_out, int out_size, void* d_ws, size_t ws_size,
                              hipStream_t stream) {
    const float* x  = (const float*)d_in[0];
    const float* fc = (const float*)d_in[1];
    const float* wq = (const float*)d_in[4];
    const float* wk = (const float*)d_in[5];
    const float* wv = (const float*)d_in[6];
    const float* wo = (const float*)d_in[7];

    float* out = (float*)d_out;
    float* kh  = out + 16777216;             // new_hidden[0]
    float* vh  = out + 33554432;             // new_hidden[1]

    u16* ws = (u16*)d_ws;
    u16* xb  = ws + 0L * SEG;
    u16* wqb = ws + 1L * SEG;
    u16* wkb = ws + 2L * SEG;
    u16* wvb = ws + 3L * SEG;
    u16* wob = ws + 4L * SEG;
    u16* xqb = ws + 5L * SEG;
    u16* xkb = ws + 6L * SEG;
    u16* xvb = ws + 7L * SEG;
    u16* qro = xb;    // q after rope
    u16* kro = wqb;   // k after rope
    u16* vt  = wkb;   // transposed V
    u16* ao  = wvb;   // attention output

    cast5<<<dim3(81920), dim3(256), 0, stream>>>(x, wq, wk, wv, wo, ws);
    gemm_bt<1><<<dim3(32, 32, 3), dim3(256), 0, stream>>>(xb, wqb, (void*)xqb);
    rope<<<dim3(32768), dim3(256), 0, stream>>>(xqb, xkb, fc, qro, kro, kh);
    vprep<<<dim3(32, 2, 64), dim3(256), 0, stream>>>(xvb, vh, vt);
    flash<<<dim3(64, 16), dim3(256), 0, stream>>>(qro, kro, vt, ao);
    gemm_bt<0><<<dim3(32, 32, 1), dim3(256), 0, stream>>>(ao, wob, (void*)out);
}